// Round 7
// baseline (401.717 us; speedup 1.0000x reference)
//
#include <hip/hip_runtime.h>

// Self-attention forward. Inputs f32: x[4,2048,1024], Wqkv[1024,3072],
// bqkv[3072], Wout[1024,1024], bout[1024]; mask[4,2048,2048] int32.
// Output f32 [4,2048,1024].
//
// Round-13: read-ahead software pipelining of the phase schedule.
//   Old phase: {reads p; barrier; MMA p; barrier} -> LDS pipe (≈550cy/CU)
//   and MFMA pipe (≈620cy/SIMD) strictly SERIALIZED -> 1400-1700cy phases,
//   MfmaUtil 30% (round-5/6 counters; fence tweaks never moved it).
//   New phase: {reads for p+1 ∥ MMA p; stage; vmcnt(N); barrier} -> both
//   pipes concurrent, lgkmcnt for the reads lands before p+1's MMA.
//   - Quadrant order q00,q10,q01,q11; double fragment sets (A:2, B:2) so
//     no read clobbers a fragment still consumed this phase.
//   - ONE barrier per phase. Counted vmcnt per phase: n128 2/4/2/4;
//     gemm256 P1:6 P3:4 P5:6 P7:4 P8:8 (FIFO retirement chains in comments).
//   - Stage->read: vmcnt retires the unit, then a barrier, then the read.
//     Read->restage: read consumed by next phase's MMA (auto lgkmcnt), all
//     waves pass >=1 barrier before the unit is restaged.

typedef __attribute__((ext_vector_type(8))) short short8;
typedef __attribute__((ext_vector_type(4))) float f32x4;
typedef unsigned short u16;

#define SEQ 2048
#define NB 4

static __device__ __forceinline__ u16 f2bf(float f) {
    unsigned int u = __builtin_bit_cast(unsigned int, f);
    u += 0x7fffu + ((u >> 16) & 1u);   // RNE
    return (u16)(u >> 16);
}
static __device__ __forceinline__ float bf2f(u16 h) {
    unsigned int u = ((unsigned int)h) << 16;
    return __builtin_bit_cast(float, u);
}

// async global->LDS, 16 bytes/lane. LDS dest = wave-uniform base + lane*16.
static __device__ __forceinline__ void gld16(u16* l, const u16* g) {
    __builtin_amdgcn_global_load_lds(
        (__attribute__((address_space(1))) void*)(g),
        (__attribute__((address_space(3))) void*)(l),
        16, 0, 0);
}

// f32 -> bf16, 8 elems/thread.
__global__ __launch_bounds__(256) void cvt_bf16(const float* __restrict__ s,
                                                u16* __restrict__ d, long n) {
    long i = ((long)blockIdx.x * 256 + threadIdx.x) * 8;
    if (i >= n) return;
    f32x4 a = *(const f32x4*)(s + i);
    f32x4 b = *(const f32x4*)(s + i + 4);
    short8 o;
    o[0] = (short)f2bf(a.x); o[1] = (short)f2bf(a.y);
    o[2] = (short)f2bf(a.z); o[3] = (short)f2bf(a.w);
    o[4] = (short)f2bf(b.x); o[5] = (short)f2bf(b.y);
    o[6] = (short)f2bf(b.z); o[7] = (short)f2bf(b.w);
    *(short8*)(d + i) = o;
}

// f32 [R][C] -> bf16 [C][R] (transpose + convert), 32x32 LDS tiles.
__global__ __launch_bounds__(256) void transpose_cvt(const float* __restrict__ in,
                                                     u16* __restrict__ out,
                                                     int R, int C) {
    __shared__ float t[32][33];
    const int c0 = blockIdx.x * 32;
    const int r0 = blockIdx.y * 32;
    const int x = threadIdx.x & 31;
    const int y = (threadIdx.x >> 5) * 4;
    #pragma unroll
    for (int i = 0; i < 4; i++)
        t[y + i][x] = in[(long)(r0 + y + i) * C + c0 + x];
    __syncthreads();
    #pragma unroll
    for (int i = 0; i < 4; i++)
        out[(long)(c0 + y + i) * R + r0 + x] = f2bf(t[x][y + i]);
}

// V slice of qkv -> vt [b][1024 d][2048 s]. bf16 32x32 tile transpose.
__global__ __launch_bounds__(256) void transpose_v(const u16* __restrict__ qkv,
                                                   u16* __restrict__ vt) {
    __shared__ u16 t[32][33];
    const int b = blockIdx.z;
    const int s0 = blockIdx.y * 32;
    const int d0 = blockIdx.x * 32;
    const int x = threadIdx.x & 31;
    const int y = (threadIdx.x >> 5) * 4;
    const u16* src = qkv + (long)b * SEQ * 3072 + 2048;
    u16* dst = vt + (long)b * 1024 * SEQ;
    #pragma unroll
    for (int i = 0; i < 4; i++)
        t[y + i][x] = src[(long)(s0 + y + i) * 3072 + d0 + x];
    __syncthreads();
    #pragma unroll
    for (int i = 0; i < 4; i++)
        dst[(long)(d0 + y + i) * SEQ + s0 + x] = t[x][y + i];
}

// bijective XCD swizzle of the flat (y*gx+x) tile id; requires nwg%8==0.
static __device__ __forceinline__ int xcd_swz(int flat, int nwg) {
    return (flat & 7) * (nwg >> 3) + (flat >> 3);
}

// bf16 MFMA GEMM, 256x256 tile, 8-phase 2-buffer read-ahead pipeline.
// C[m][n] = sum_k A[m][k] * Bt[n][k]   (Bt = B^T, [N][K] row-major).
// EPI 0: bf16 out + optional f32 bias.  EPI 1: bf16 out, *scale.
// EPI 2: f32 out + f32 bias.
// Requires: M,N multiples of 256; K multiple of 128; (gx*gy)%8==0.
//
// Stage plan per iter j (buf0=tile 2j, buf1=2j+1), 2 gld16 each:
//   p1:buf1.A0(+64) p2:buf1.B1(+64) p3:buf0.B0(+128) p4:buf0.A1(+128)
//   p5:buf0.A0(+128) p6:buf0.B1(+128) p7:buf1.B0(+192) p8:buf1.A1(+192)
// Reads (for NEXT phase's MMA): p1:a1<-buf0.A1[p4(j-1)] p2:b1<-buf0.B1
//   [p6(j-1)] p4:a0<-buf1.A0[p1(j)],b0<-buf1.B0[p7(j-1)] p5:a1<-buf1.A1
//   [p8(j-1)] p6:b1<-buf1.B1[p2(j)] p8:a0<-buf0.A0[p5(j)],b0<-buf0.B0[p3(j)]
// vmcnt (phase end, before next barrier), FIFO-derived:
//   p1:6 (retires p6(j-1); younger p7,p8,p1)   p3:4 (retires p1(j))
//   p5:6 (retires p2(j))   p7:4 (retires p5(j))   p8:8 (retires p4(j))
//   p3's also covers p8(j-1) for p5's read; p7's covers p3(j).
template<int EPI>
__global__ __launch_bounds__(512, 2) void gemm256(
    const u16* __restrict__ Ap, long lda, long aBatch,
    const u16* __restrict__ Bp, long ldb, long bBatch,
    void* __restrict__ Cp, long ldc, long cBatch,
    const float* __restrict__ bias,
    float scale, int K)
{
    // 2 bufs x (A[256][64] + B[256][64]) bf16 = 2 x 64 KB = 128 KB.
    __shared__ __attribute__((aligned(16))) u16 lds[65536];

    const int tid  = threadIdx.x;
    const int lane = tid & 63;
    const int wave = tid >> 6;          // 0..7
    const int wrq  = wave >> 1;         // 0..3: 32-row band within quadrant
    const int wcq  = wave & 1;          // 0..1: 64-col band within quadrant
    const int m16  = lane & 15;
    const int quad = lane >> 4;
    const int b    = blockIdx.z;

    const int gx = gridDim.x;
    const int flat = xcd_swz(blockIdx.y * gx + blockIdx.x, gx * gridDim.y);
    const long m0  = (long)(flat / gx) * 256;
    const long n0  = (long)(flat % gx) * 256;

    const u16* A = Ap + (long)b * aBatch;
    const u16* B = Bp + (long)b * bBatch;

    // staging lane constants (inverse-swizzled global source):
    const int srow   = lane >> 3;
    const int schunk = (lane & 7) ^ srow;
    const u16* aP = A + (m0 + wave * 8 + srow) * lda + schunk * 8;
    const u16* bP = B + (n0 + wave * 8 + srow) * ldb + schunk * 8;

    // swizzled ds_read chunk offset (row&7 == m16&7 for all frag rows):
    const int cswz = (quad ^ (m16 & 7)) * 8;    // ks=1 -> cswz ^ 32
    const int arow = wrq * 32 + m16;
    const int brow = wcq * 64 + m16;

    short8 a0[2][2], a1[2][2], b0[2][4], b1[2][4];  // [ks][mi] / [ks][ni]
    f32x4 acc[2][2][2][4];                          // [qr][qc][mi][ni]
    #pragma unroll
    for (int i = 0; i < 2; i++)
        #pragma unroll
        for (int j = 0; j < 2; j++)
            #pragma unroll
            for (int mi = 0; mi < 2; mi++)
                #pragma unroll
                for (int ni = 0; ni < 4; ni++)
                    acc[i][j][mi][ni] = (f32x4){0.f, 0.f, 0.f, 0.f};

    auto STAGE_A = [&](int buf, int h, int toff) {
        u16* l = (u16*)lds + buf * 32768 + h * 8192 + wave * 512;
        const u16* g = aP + (long)(h * 128) * lda + toff;
        gld16(l, g);
        gld16(l + 4096, g + (long)64 * lda);
    };
    auto STAGE_B = [&](int buf, int h, int toff) {
        u16* l = (u16*)lds + buf * 32768 + 16384 + h * 8192 + wave * 512;
        const u16* g = bP + (long)(h * 128) * ldb + toff;
        gld16(l, g);
        gld16(l + 4096, g + (long)64 * ldb);
    };
    auto RDA = [&](short8 (&d)[2][2], int buf, int qr) {
        const u16* p = (const u16*)lds + buf * 32768 + qr * 8192 + arow * 64;
        d[0][0] = *(const short8*)(p + cswz);
        d[0][1] = *(const short8*)(p + 1024 + cswz);
        d[1][0] = *(const short8*)(p + (cswz ^ 32));
        d[1][1] = *(const short8*)(p + 1024 + (cswz ^ 32));
    };
    auto RDB = [&](short8 (&d)[2][4], int buf, int qc) {
        const u16* p = (const u16*)lds + buf * 32768 + 16384 + qc * 8192 + brow * 64;
        #pragma unroll
        for (int ks = 0; ks < 2; ks++)
            #pragma unroll
            for (int ni = 0; ni < 4; ni++)
                d[ks][ni] = *(const short8*)(p + ni * 1024 + (cswz ^ (ks * 32)));
    };
    auto MMA = [&](f32x4 (&c)[2][4], const short8 (&a)[2][2],
                   const short8 (&bb)[2][4]) {
        __builtin_amdgcn_s_setprio(1);
        #pragma unroll
        for (int ks = 0; ks < 2; ks++)
            #pragma unroll
            for (int mi = 0; mi < 2; mi++)
                #pragma unroll
                for (int ni = 0; ni < 4; ni++)
                    c[mi][ni] = __builtin_amdgcn_mfma_f32_16x16x32_bf16(
                        a[ks][mi], bb[ks][ni], c[mi][ni], 0, 0, 0);
        __builtin_amdgcn_s_setprio(0);
    };

    const int nt = K >> 6;        // 64-wide K-tiles (nt even, >= 4)
    const int niter = nt >> 1;

    // prologue: FIFO = B0,A1,A0,B1 (buf0) then buf1.B0, buf1.A1.
    // vmcnt(4) retires buf0 entirely (pre-reads + p1's read need it).
    STAGE_B(0, 0, 0); STAGE_A(0, 1, 0); STAGE_A(0, 0, 0); STAGE_B(0, 1, 0);
    STAGE_B(1, 0, 64); STAGE_A(1, 1, 64);
    asm volatile("s_waitcnt vmcnt(4)");
    __builtin_amdgcn_s_barrier();
    RDA(a0, 0, 0); RDB(b0, 0, 0);

    #pragma unroll 1
    for (int j = 0; j < niter - 1; ++j) {
        // p1: q(0,0) [a0,b0] ; read a1 (buf0.A1)
        RDA(a1, 0, 1); STAGE_A(1, 0, 64);
        MMA(acc[0][0], a0, b0);
        asm volatile("s_waitcnt vmcnt(6)");
        __builtin_amdgcn_s_barrier();
        // p2: q(1,0) [a1,b0] ; read b1 (buf0.B1)
        RDB(b1, 0, 1); STAGE_B(1, 1, 64);
        MMA(acc[1][0], a1, b0);
        __builtin_amdgcn_s_barrier();
        // p3: q(0,1) [a0,b1]
        STAGE_B(0, 0, 128);
        MMA(acc[0][1], a0, b1);
        asm volatile("s_waitcnt vmcnt(4)");
        __builtin_amdgcn_s_barrier();
        // p4: q(1,1) [a1,b1] ; read a0,b0 (buf1 q0)
        RDA(a0, 1, 0); RDB(b0, 1, 0); STAGE_A(0, 1, 128);
        MMA(acc[1][1], a1, b1);
        __builtin_amdgcn_s_barrier();
        // p5: q(0,0) [a0,b0] buf1 ; read a1 (buf1.A1)
        RDA(a1, 1, 1); STAGE_A(0, 0, 128);
        MMA(acc[0][0], a0, b0);
        asm volatile("s_waitcnt vmcnt(6)");
        __builtin_amdgcn_s_barrier();
        // p6: q(1,0) ; read b1 (buf1.B1)
        RDB(b1, 1, 1); STAGE_B(0, 1, 128);
        MMA(acc[1][0], a1, b0);
        __builtin_amdgcn_s_barrier();
        // p7: q(0,1)
        STAGE_B(1, 0, 192);
        MMA(acc[0][1], a0, b1);
        asm volatile("s_waitcnt vmcnt(4)");
        __builtin_amdgcn_s_barrier();
        // p8: q(1,1) ; read a0,b0 (buf0 q0, tile 2j+2)
        RDA(a0, 0, 0); RDB(b0, 0, 0); STAGE_A(1, 1, 192);
        MMA(acc[1][1], a1, b1);
        asm volatile("s_waitcnt vmcnt(8)");
        __builtin_amdgcn_s_barrier();

        aP += 128; bP += 128;
    }

    // peeled final iteration (buf0=tile nt-2, buf1=nt-1): p1,p2 stages real
    // (+64 = nt-1); p3..p8 stages dead (clamped +64, counts preserved);
    // p8's next-tile reads skipped.
    {
        RDA(a1, 0, 1); STAGE_A(1, 0, 64);
        MMA(acc[0][0], a0, b0);
        asm volatile("s_waitcnt vmcnt(6)");
        __builtin_amdgcn_s_barrier();
        RDB(b1, 0, 1); STAGE_B(1, 1, 64);
        MMA(acc[1][0], a1, b0);
        __builtin_amdgcn_s_barrier();
        STAGE_B(0, 0, 64);
        MMA(acc[0][1], a0, b1);
        asm volatile("s_waitcnt vmcnt(4)");
        __builtin_amdgcn_s_barrier();
        RDA(a0, 1, 0); RDB(b0, 1, 0); STAGE_A(0, 1, 64);
        MMA(acc[1][1], a1, b1);
        __builtin_amdgcn_s_barrier();
        RDA(a1, 1, 1); STAGE_A(0, 0, 64);
        MMA(acc[0][0], a0, b0);
        asm volatile("s_waitcnt vmcnt(6)");
        __builtin_amdgcn_s_barrier();
        RDB(b1, 1, 1); STAGE_B(0, 1, 64);
        MMA(acc[1][0], a1, b0);
        __builtin_amdgcn_s_barrier();
        STAGE_B(1, 0, 64);
        MMA(acc[0][1], a0, b1);
        __builtin_amdgcn_s_barrier();
        MMA(acc[1][1], a1, b1);
    }

    // drain async LDS writes before epilogue/endpgm (LDS realloc hazard)
    asm volatile("s_waitcnt vmcnt(0)");

    // D mapping per 16x16 frag: col = lane&15, row = quad*4 + r.
    #pragma unroll
    for (int qr = 0; qr < 2; qr++) {
        const long row0 = m0 + qr * 128 + wrq * 32 + quad * 4;
        #pragma unroll
        for (int qc = 0; qc < 2; qc++) {
            #pragma unroll
            for (int ni = 0; ni < 4; ni++) {
                const long col = n0 + qc * 128 + wcq * 64 + ni * 16 + m16;
                if (EPI == 0) {
                    u16* C = (u16*)Cp + (long)b * cBatch;
                    const float bv = bias ? bias[col] : 0.f;
                    #pragma unroll
                    for (int mi = 0; mi < 2; mi++)
                        #pragma unroll
                        for (int r = 0; r < 4; r++)
                            C[(row0 + mi * 16 + r) * ldc + col] =
                                f2bf(acc[qr][qc][mi][ni][r] + bv);
                } else if (EPI == 1) {
                    u16* C = (u16*)Cp + (long)b * cBatch;
                    #pragma unroll
                    for (int mi = 0; mi < 2; mi++)
                        #pragma unroll
                        for (int r = 0; r < 4; r++)
                            C[(row0 + mi * 16 + r) * ldc + col] =
                                f2bf(acc[qr][qc][mi][ni][r] * scale);
                } else {
                    float* C = (float*)Cp + (long)b * cBatch;
                    const float bv = bias ? bias[col] : 0.f;
                    #pragma unroll
                    for (int mi = 0; mi < 2; mi++)
                        #pragma unroll
                        for (int r = 0; r < 4; r++)
                            C[(row0 + mi * 16 + r) * ldc + col] =
                                acc[qr][qc][mi][ni][r] + bv;
                }
            }
        }
    }
}

// bf16 MFMA GEMM, 256x128 tile, 4-phase 2-buffer read-ahead pipeline.
// Stage plan per iter j (buf0=2j, buf1=2j+1): S1=p1:buf1.A1(+64)
//   S2=p2:buf0.{A0,B0}(+128) S3=p3:buf0.A1(+128) S4=p4:buf1.{A0,B0}(+192)
// Reads (for NEXT phase): p1:aB<-buf0.A1[S3(j-1)] p2:aA<-buf1.A0,b1<-
//   buf1.B0[S4(j-1)] p3:aB<-buf1.A1[S1(j)] p4:aA<-buf0.A0,b0<-buf0.B0[S2(j)]
// vmcnt per phase end: p1:2 (retires S4(j-1)) p2:4 (S1) p3:2 (S2) p4:4 (S3).
// Requires: M%256==0, N%128==0, K%128==0, (gx*gy)%8==0.
template<int EPI>
__global__ __launch_bounds__(512, 2) void gemm256n128(
    const u16* __restrict__ Ap, long lda, long aBatch,
    const u16* __restrict__ Bp, long ldb, long bBatch,
    void* __restrict__ Cp, long ldc, long cBatch,
    const float* __restrict__ bias,
    float scale, int K)
{
    // 2 bufs x (A[256][64] + B[128][64]) bf16 = 2 x 48 KB = 96 KB.
    __shared__ __attribute__((aligned(16))) u16 lds[49152];

    const int tid  = threadIdx.x;
    const int lane = tid & 63;
    const int wave = tid >> 6;          // 0..7
    const int wrq  = wave >> 1;         // 0..3: 32-row band within quadrant
    const int wcq  = wave & 1;          // 0..1: 64-col band within 128 cols
    const int m16  = lane & 15;
    const int quad = lane >> 4;
    const int b    = blockIdx.z;

    const int gx = gridDim.x;
    const int flat = xcd_swz(blockIdx.y * gx + blockIdx.x, gx * gridDim.y);
    const long m0  = (long)(flat / gx) * 256;
    const long n0  = (long)(flat % gx) * 128;

    const u16* A = Ap + (long)b * aBatch;
    const u16* B = Bp + (long)b * bBatch;

    const int srow   = lane >> 3;
    const int schunk = (lane & 7) ^ srow;
    const u16* aP = A + (m0 + wave * 8 + srow) * lda + schunk * 8;
    const u16* bP = B + (n0 + wave * 8 + srow) * ldb + schunk * 8;

    const int cswz = (quad ^ (m16 & 7)) * 8;
    const int arow = wrq * 32 + m16;
    const int brow = wcq * 64 + m16;

    short8 aA[2][2], aB[2][2], b0[2][4], b1[2][4];
    f32x4 acc[2][2][4];                 // [qr][mi][ni]
    #pragma unroll
    for (int qr = 0; qr < 2; qr++)
        #pragma unroll
        for (int mi = 0; mi < 2; mi++)
            #pragma unroll
            for (int ni = 0; ni < 4; ni++)
                acc[qr][mi][ni] = (f32x4){0.f, 0.f, 0.f, 0.f};

    auto STAGE_A = [&](int buf, int h, int toff) {
        u16* l = (u16*)lds + buf * 24576 + h * 8192 + wave * 512;
        const u16* g = aP + (long)(h * 128) * lda + toff;
        gld16(l, g);
        gld16(l + 4096, g + (long)64 * lda);
    };
    auto STAGE_B = [&](int buf, int toff) {
        u16* l = (u16*)lds + buf * 24576 + 16384 + wave * 512;
        const u16* g = bP + toff;
        gld16(l, g);
        gld16(l + 4096, g + (long)64 * ldb);
    };
    auto RDA = [&](short8 (&d)[2][2], int buf, int qr) {
        const u16* p = (const u16*)lds + buf * 24576 + qr * 8192 + arow * 64;
        d[0][0] = *(const short8*)(p + cswz);
        d[0][1] = *(const short8*)(p + 1024 + cswz);
        d[1][0] = *(const short8*)(p + (cswz ^ 32));
        d[1][1] = *(const short8*)(p + 1024 + (cswz ^ 32));
    };
    auto RDB = [&](short8 (&d)[2][4], int buf) {
        const u16* p = (const u16*)lds + buf * 24576 + 16384 + brow * 64;
        #pragma unroll
        for (int ks = 0; ks < 2; ks++)
            #pragma unroll
            for (int ni = 0; ni < 4; ni++)
                d[ks][ni] = *(const short8*)(p + ni * 1024 + (cswz ^ (ks * 32)));
    };
    auto MMA = [&](f32x4 (&c)[2][4], const short8 (&a)[2][2],
                   const short8 (&bb)[2][4]) {
        __builtin_amdgcn_s_setprio(1);
        #pragma unroll
        for (int ks = 0; ks < 2; ks++)
            #pragma unroll
            for (int mi = 0; mi < 2; mi++)
                #pragma unroll
                for (int ni = 0; ni < 4; ni++)
                    c[mi][ni] = __builtin_amdgcn_mfma_f32_16x16x32_bf16(
                        a[ks][mi], bb[ks][ni], c[mi][ni], 0, 0, 0);
        __builtin_amdgcn_s_setprio(0);
    };

    const int nt = K >> 6;
    const int niter = nt >> 1;

    // prologue: FIFO = buf0.A0,B0 (4), buf0.A1 (2), buf1.A0,B0 (4).
    // vmcnt(4) retires buf0 entirely (pre-reads + p1's read).
    STAGE_A(0, 0, 0); STAGE_B(0, 0); STAGE_A(0, 1, 0);
    STAGE_A(1, 0, 64); STAGE_B(1, 64);
    asm volatile("s_waitcnt vmcnt(4)");
    __builtin_amdgcn_s_barrier();
    RDA(aA, 0, 0); RDB(b0, 0);

    #pragma unroll 1
    for (int j = 0; j < niter - 1; ++j) {
        // p1: buf0.q0 [aA,b0] ; read aB<-buf0.A1
        RDA(aB, 0, 1); STAGE_A(1, 1, 64);
        MMA(acc[0], aA, b0);
        asm volatile("s_waitcnt vmcnt(2)");
        __builtin_amdgcn_s_barrier();
        // p2: buf0.q1 [aB,b0] ; read aA<-buf1.A0, b1<-buf1.B
        RDA(aA, 1, 0); RDB(b1, 1); STAGE_A(0, 0, 128); STAGE_B(0, 128);
        MMA(acc[1], aB, b0);
        asm volatile("s_waitcnt vmcnt(4)");
        __builtin_amdgcn_s_barrier();
        // p3: buf1.q0 [aA,b1] ; read aB<-buf1.A1
        RDA(aB, 1, 1); STAGE_A(0, 1, 128);
        MMA(acc[0], aA, b1);
        asm volatile("s_waitcnt vmcnt(2)");
        __builtin_amdgcn_s_barrier();
        // p4: buf1.q1 [aB,b1] ; read aA<-buf0.A0, b0<-buf0.B (tile 2j+2)
        RDA(aA, 0, 0); RDB(b0, 0); STAGE_A(1, 0, 192); STAGE_B(1, 192);
        MMA(acc[1], aB, b1);
        asm volatile("s_waitcnt vmcnt(4)");
        __builtin_amdgcn_s_barrier();

        aP += 128; bP += 128;
    }

    // peeled final iteration (buf0=nt-2, buf1=nt-1): p1 stage real;
    // p2..p4 dead (clamped +64); p4's next-tile reads skipped.
    {
        RDA(aB, 0, 1); STAGE_A(1, 1, 64);
        MMA(acc[0], aA, b0);
        asm volatile("s_waitcnt vmcnt(2)");
        __builtin_amdgcn_s_barrier();
        RDA(aA, 1, 0); RDB(b1, 1); STAGE_A(0, 0, 64); STAGE_B(0, 64);
        MMA(acc[1], aB, b0);
        asm volatile("s_waitcnt vmcnt(4)");
        __builtin_amdgcn_s_barrier();
        RDA(aB, 1, 1); STAGE_A(0, 1, 64);
        MMA(acc[0], aA, b1);
        asm volatile("s_waitcnt vmcnt(2)");
        __builtin_amdgcn_s_barrier();
        MMA(acc[1], aB, b1);
    }

    // drain async LDS writes before epilogue/endpgm (LDS realloc hazard)
    asm volatile("s_waitcnt vmcnt(0)");

    // D mapping per 16x16 frag: col = lane&15, row = quad*4 + r.
    #pragma unroll
    for (int qr = 0; qr < 2; qr++) {
        const long row0 = m0 + qr * 128 + wrq * 32 + quad * 4;
        #pragma unroll
        for (int ni = 0; ni < 4; ni++) {
            const long col = n0 + wcq * 64 + ni * 16 + m16;
            if (EPI == 0) {
                u16* C = (u16*)Cp + (long)b * cBatch;
                const float bv = bias ? bias[col] : 0.f;
                #pragma unroll
                for (int mi = 0; mi < 2; mi++)
                    #pragma unroll
                    for (int r = 0; r < 4; r++)
                        C[(row0 + mi * 16 + r) * ldc + col] =
                            f2bf(acc[qr][mi][ni][r] + bv);
            } else if (EPI == 1) {
                u16* C = (u16*)Cp + (long)b * cBatch;
                #pragma unroll
                for (int mi = 0; mi < 2; mi++)
                    #pragma unroll
                    for (int r = 0; r < 4; r++)
                        C[(row0 + mi * 16 + r) * ldc + col] =
                            f2bf(acc[qr][mi][ni][r] * scale);
            } else {
                float* C = (float*)Cp + (long)b * cBatch;
                const float bv = bias ? bias[col] : 0.f;
                #pragma unroll
                for (int mi = 0; mi < 2; mi++)
                    #pragma unroll
                    for (int r = 0; r < 4; r++)
                        C[(row0 + mi * 16 + r) * ldc + col] =
                            acc[qr][mi][ni][r] + bv;
            }
        }
    }
}

// in-place masked row softmax over 2048 bf16 (f32 math). 1 block per row.
__global__ __launch_bounds__(256) void softmax2048(u16* __restrict__ S,
                                                   const int* __restrict__ mask) {
    const long row = blockIdx.x;
    u16* p = S + row * SEQ;
    const int* mrow = mask + row * SEQ;
    const int tid = threadIdx.x;

    short8 v = *(const short8*)(p + tid * 8);
    uint4 mw0 = *(const uint4*)(mrow + tid * 8);
    uint4 mw1 = *(const uint4*)(mrow + tid * 8 + 4);
    const unsigned int* mwv = (const unsigned int*)&mw0;

    float f[8];
    #pragma unroll
    for (int j = 0; j < 8; j++) {
        const unsigned int mv = (j < 4) ? mwv[j] : ((const unsigned int*)&mw1)[j - 4];
        f[j] = (mv == 0u) ? 1e-10f : bf2f((u16)v[j]);
    }

    float m = f[0];
    #pragma unroll
    for (int j = 1; j < 8; j++) m = fmaxf(m, f[j]);
    #pragma unroll
    for (int i = 1; i < 64; i <<= 1) m = fmaxf(m, __shfl_xor(m, i));

    __shared__ float redm[4], reds[4];
    if ((tid & 63) == 0) redm[tid >> 6] = m;
    __syncthreads();
    m = fmaxf(fmaxf(redm[0], redm[1]), fmaxf(redm[2], redm[3]));

    float e[8], s = 0.f;
    #pragma unroll
    for (int j = 0; j < 8; j++) { e[j] = __expf(f[j] - m); s += e[j]; }
    #pragma unroll
    for (int i = 1; i < 64; i <<= 1) s += __shfl_xor(s, i);
    if ((tid & 63) == 0) reds[tid >> 6] = s;
    __syncthreads();
    s = reds[0] + reds[1] + reds[2] + reds[3];

    const float inv = 1.f / s;
    short8 o;
    #pragma unroll
    for (int j = 0; j < 8; j++) o[j] = (short)f2bf(e[j] * inv);
    *(short8*)(p + tid * 8) = o;
}

extern "C" void kernel_launch(void* const* d_in, const int* in_sizes, int n_in,
                              void* d_out, int out_size, void* d_ws, size_t ws_size,
                              hipStream_t stream) {
    const float* x    = (const float*)d_in[0];
    const int*   mask = (const int*)d_in[1];
    const float* Wqkv = (const float*)d_in[2];
    const float* bqkv = (const float*)d_in[3];
    const float* Wout = (const float*)d_in[4];
    const float* bout = (const float*)d_in[5];
    float* out = (float*)d_out;

    char* ws = (char*)d_ws;
    // ws layout, total 102,760,448 bytes:
    //   [0,        16777216) xh  bf16 [8192][1024]          (cvt -> K1)
    //   [16777216, 23068672) wqt bf16 [3072][1024]          (cvt -> K1)
    //   [0,        33554432) sc  bf16 [4][2048][2048]       (K2 -> K4; xh,wqt dead)
    //   [33554432, 35651584) wot bf16 [1024][1024]          (cvt -> K5)
    //   [35651584, 85983232) qkv bf16 [8192][3072]          (K1 -> K2)
    //   [35651584, 52428800) attn bf16 [8192][1024]         (K4 -> K5; qkv dead)
    //   [85983232,102760448) vt  bf16 [4][1024][2048]       (transpose_v -> K4)
    u16* xh   = (u16*)(ws + 0);
    u16* wqt  = (u16*)(ws + 16777216);
    u16* sc   = (u16*)(ws + 0);
    u16* wot  = (u16*)(ws + 33554432);
    u16* qkv  = (u16*)(ws + 35651584);
    u16* attn = (u16*)(ws + 35651584);
    u16* vt   = (u16*)(ws + 85983232);

    cvt_bf16<<<4096, 256, 0, stream>>>(x, xh, 8388608);
    transpose_cvt<<<dim3(96, 32), 256, 0, stream>>>(Wqkv, wqt, 1024, 3072);
    transpose_cvt<<<dim3(32, 32), 256, 0, stream>>>(Wout, wot, 1024, 1024);

    // K1: qkv = x @ Wqkv + bqkv   (M=8192, N=3072, K=1024), bf16 out
    gemm256n128<0><<<dim3(24, 32, 1), 512, 0, stream>>>(
        xh, 1024, 0, wqt, 1024, 0, qkv, 3072, 0, bqkv, 1.f, 1024);

    // V slice -> vt [b][d][s]
    transpose_v<<<dim3(32, 64, NB), 256, 0, stream>>>(qkv, vt);

    // K2: sc[b] = (Q[b] @ K[b]^T)/32   (M=N=2048, K=1024), bf16 out
    gemm256<1><<<dim3(8, 8, NB), 512, 0, stream>>>(
        qkv, 3072, (long)SEQ * 3072, qkv + 1024, 3072, (long)SEQ * 3072,
        sc, SEQ, (long)SEQ * SEQ, nullptr, 0.03125f, 1024);

    // K3: masked softmax rows (mask==0 -> 1e-10, f32 math, bf16 storage)
    softmax2048<<<dim3(NB * SEQ), 256, 0, stream>>>(sc, mask);

    // K4: attn[b] = P[b] @ V[b]   (M=2048, N=1024, K=2048), bf16 out
    gemm256n128<0><<<dim3(8, 8, NB), 512, 0, stream>>>(
        sc, SEQ, (long)SEQ * SEQ, vt, SEQ, (long)1024 * SEQ,
        attn, 1024, (long)SEQ * 1024, nullptr, 1.f, 2048);

    // K5: out = attn @ Wout + bout   (M=8192, N=1024, K=1024), f32 out
    gemm256n128<2><<<dim3(8, 32, 1), 512, 0, stream>>>(
        attn, 1024, 0, wot, 1024, 0, out, 1024, 0, bout, 1.f, 1024);
}

// Round 8
// 312.110 us; speedup vs baseline: 1.2871x; 1.2871x over previous
//
#include <hip/hip_runtime.h>

// Self-attention forward. Inputs f32: x[4,2048,1024], Wqkv[1024,3072],
// bqkv[3072], Wout[1024,1024], bout[1024]; mask[4,2048,2048] int32.
// Output f32 [4,2048,1024].
//
// Round-14: single GEMM kernel everywhere.
//   Round-7 post-mortem: the 256x256 read-ahead variant spilled (acc 128
//   AGPR + doubled frag sets 96 VGPR > 256/wave budget -> FETCH 224MB /
//   WRITE 280MB of scratch, K2 at 130us, MfmaUtil 10%). The 256x128
//   read-ahead variant fits (acc 64 AGPR) and improved K1/K4/K5 by ~18us
//   (inferred: 402 = 335 - 45 + 130 - 18). So: delete gemm256, run K2 on
//   gemm256n128<1> with grid (16,8,4) = 512 blocks = 2.0 exact rounds.
//   All GEMM grids are exact round multiples: 768/512/256/256.

typedef __attribute__((ext_vector_type(8))) short short8;
typedef __attribute__((ext_vector_type(4))) float f32x4;
typedef unsigned short u16;

#define SEQ 2048
#define NB 4

static __device__ __forceinline__ u16 f2bf(float f) {
    unsigned int u = __builtin_bit_cast(unsigned int, f);
    u += 0x7fffu + ((u >> 16) & 1u);   // RNE
    return (u16)(u >> 16);
}
static __device__ __forceinline__ float bf2f(u16 h) {
    unsigned int u = ((unsigned int)h) << 16;
    return __builtin_bit_cast(float, u);
}

// async global->LDS, 16 bytes/lane. LDS dest = wave-uniform base + lane*16.
static __device__ __forceinline__ void gld16(u16* l, const u16* g) {
    __builtin_amdgcn_global_load_lds(
        (__attribute__((address_space(1))) void*)(g),
        (__attribute__((address_space(3))) void*)(l),
        16, 0, 0);
}

// f32 -> bf16, 8 elems/thread.
__global__ __launch_bounds__(256) void cvt_bf16(const float* __restrict__ s,
                                                u16* __restrict__ d, long n) {
    long i = ((long)blockIdx.x * 256 + threadIdx.x) * 8;
    if (i >= n) return;
    f32x4 a = *(const f32x4*)(s + i);
    f32x4 b = *(const f32x4*)(s + i + 4);
    short8 o;
    o[0] = (short)f2bf(a.x); o[1] = (short)f2bf(a.y);
    o[2] = (short)f2bf(a.z); o[3] = (short)f2bf(a.w);
    o[4] = (short)f2bf(b.x); o[5] = (short)f2bf(b.y);
    o[6] = (short)f2bf(b.z); o[7] = (short)f2bf(b.w);
    *(short8*)(d + i) = o;
}

// f32 [R][C] -> bf16 [C][R] (transpose + convert), 32x32 LDS tiles.
__global__ __launch_bounds__(256) void transpose_cvt(const float* __restrict__ in,
                                                     u16* __restrict__ out,
                                                     int R, int C) {
    __shared__ float t[32][33];
    const int c0 = blockIdx.x * 32;
    const int r0 = blockIdx.y * 32;
    const int x = threadIdx.x & 31;
    const int y = (threadIdx.x >> 5) * 4;
    #pragma unroll
    for (int i = 0; i < 4; i++)
        t[y + i][x] = in[(long)(r0 + y + i) * C + c0 + x];
    __syncthreads();
    #pragma unroll
    for (int i = 0; i < 4; i++)
        out[(long)(c0 + y + i) * R + r0 + x] = f2bf(t[x][y + i]);
}

// V slice of qkv -> vt [b][1024 d][2048 s]. bf16 32x32 tile transpose.
__global__ __launch_bounds__(256) void transpose_v(const u16* __restrict__ qkv,
                                                   u16* __restrict__ vt) {
    __shared__ u16 t[32][33];
    const int b = blockIdx.z;
    const int s0 = blockIdx.y * 32;
    const int d0 = blockIdx.x * 32;
    const int x = threadIdx.x & 31;
    const int y = (threadIdx.x >> 5) * 4;
    const u16* src = qkv + (long)b * SEQ * 3072 + 2048;
    u16* dst = vt + (long)b * 1024 * SEQ;
    #pragma unroll
    for (int i = 0; i < 4; i++)
        t[y + i][x] = src[(long)(s0 + y + i) * 3072 + d0 + x];
    __syncthreads();
    #pragma unroll
    for (int i = 0; i < 4; i++)
        dst[(long)(d0 + y + i) * SEQ + s0 + x] = t[x][y + i];
}

// bijective XCD swizzle of the flat (y*gx+x) tile id; requires nwg%8==0.
static __device__ __forceinline__ int xcd_swz(int flat, int nwg) {
    return (flat & 7) * (nwg >> 3) + (flat >> 3);
}

// bf16 MFMA GEMM, 256x128 tile, 4-phase 2-buffer read-ahead pipeline.
// C[m][n] = sum_k A[m][k] * Bt[n][k]   (Bt = B^T, [N][K] row-major).
// EPI 0: bf16 out + optional f32 bias.  EPI 1: bf16 out, *scale.
// EPI 2: f32 out + f32 bias.
// Stage plan per iter j (buf0=2j, buf1=2j+1): S1=p1:buf1.A1(+64)
//   S2=p2:buf0.{A0,B0}(+128) S3=p3:buf0.A1(+128) S4=p4:buf1.{A0,B0}(+192)
// Reads (for NEXT phase): p1:aB<-buf0.A1[S3(j-1)] p2:aA<-buf1.A0,b1<-
//   buf1.B0[S4(j-1)] p3:aB<-buf1.A1[S1(j)] p4:aA<-buf0.A0,b0<-buf0.B0[S2(j)]
// vmcnt per phase end: p1:2 (retires S4(j-1)) p2:4 (S1) p3:2 (S2) p4:4 (S3).
// Registers: acc 64 AGPR + frags 96 VGPR + addr ~30 -> fits 256/wave
// (1 block/CU, 2 waves/SIMD). The 256x256 variant of this schedule spills.
// Requires: M%256==0, N%128==0, K%128==0, (gx*gy)%8==0.
template<int EPI>
__global__ __launch_bounds__(512, 2) void gemm256n128(
    const u16* __restrict__ Ap, long lda, long aBatch,
    const u16* __restrict__ Bp, long ldb, long bBatch,
    void* __restrict__ Cp, long ldc, long cBatch,
    const float* __restrict__ bias,
    float scale, int K)
{
    // 2 bufs x (A[256][64] + B[128][64]) bf16 = 2 x 48 KB = 96 KB.
    __shared__ __attribute__((aligned(16))) u16 lds[49152];

    const int tid  = threadIdx.x;
    const int lane = tid & 63;
    const int wave = tid >> 6;          // 0..7
    const int wrq  = wave >> 1;         // 0..3: 32-row band within quadrant
    const int wcq  = wave & 1;          // 0..1: 64-col band within 128 cols
    const int m16  = lane & 15;
    const int quad = lane >> 4;
    const int b    = blockIdx.z;

    const int gx = gridDim.x;
    const int flat = xcd_swz(blockIdx.y * gx + blockIdx.x, gx * gridDim.y);
    const long m0  = (long)(flat / gx) * 256;
    const long n0  = (long)(flat % gx) * 128;

    const u16* A = Ap + (long)b * aBatch;
    const u16* B = Bp + (long)b * bBatch;

    const int srow   = lane >> 3;
    const int schunk = (lane & 7) ^ srow;
    const u16* aP = A + (m0 + wave * 8 + srow) * lda + schunk * 8;
    const u16* bP = B + (n0 + wave * 8 + srow) * ldb + schunk * 8;

    const int cswz = (quad ^ (m16 & 7)) * 8;
    const int arow = wrq * 32 + m16;
    const int brow = wcq * 64 + m16;

    short8 aA[2][2], aB[2][2], b0[2][4], b1[2][4];
    f32x4 acc[2][2][4];                 // [qr][mi][ni]
    #pragma unroll
    for (int qr = 0; qr < 2; qr++)
        #pragma unroll
        for (int mi = 0; mi < 2; mi++)
            #pragma unroll
            for (int ni = 0; ni < 4; ni++)
                acc[qr][mi][ni] = (f32x4){0.f, 0.f, 0.f, 0.f};

    auto STAGE_A = [&](int buf, int h, int toff) {
        u16* l = (u16*)lds + buf * 24576 + h * 8192 + wave * 512;
        const u16* g = aP + (long)(h * 128) * lda + toff;
        gld16(l, g);
        gld16(l + 4096, g + (long)64 * lda);
    };
    auto STAGE_B = [&](int buf, int toff) {
        u16* l = (u16*)lds + buf * 24576 + 16384 + wave * 512;
        const u16* g = bP + toff;
        gld16(l, g);
        gld16(l + 4096, g + (long)64 * ldb);
    };
    auto RDA = [&](short8 (&d)[2][2], int buf, int qr) {
        const u16* p = (const u16*)lds + buf * 24576 + qr * 8192 + arow * 64;
        d[0][0] = *(const short8*)(p + cswz);
        d[0][1] = *(const short8*)(p + 1024 + cswz);
        d[1][0] = *(const short8*)(p + (cswz ^ 32));
        d[1][1] = *(const short8*)(p + 1024 + (cswz ^ 32));
    };
    auto RDB = [&](short8 (&d)[2][4], int buf) {
        const u16* p = (const u16*)lds + buf * 24576 + 16384 + brow * 64;
        #pragma unroll
        for (int ks = 0; ks < 2; ks++)
            #pragma unroll
            for (int ni = 0; ni < 4; ni++)
                d[ks][ni] = *(const short8*)(p + ni * 1024 + (cswz ^ (ks * 32)));
    };
    auto MMA = [&](f32x4 (&c)[2][4], const short8 (&a)[2][2],
                   const short8 (&bb)[2][4]) {
        __builtin_amdgcn_s_setprio(1);
        #pragma unroll
        for (int ks = 0; ks < 2; ks++)
            #pragma unroll
            for (int mi = 0; mi < 2; mi++)
                #pragma unroll
                for (int ni = 0; ni < 4; ni++)
                    c[mi][ni] = __builtin_amdgcn_mfma_f32_16x16x32_bf16(
                        a[ks][mi], bb[ks][ni], c[mi][ni], 0, 0, 0);
        __builtin_amdgcn_s_setprio(0);
    };

    const int nt = K >> 6;
    const int niter = nt >> 1;

    // prologue: FIFO = buf0.A0,B0 (4), buf0.A1 (2), buf1.A0,B0 (4).
    // vmcnt(4) retires buf0 entirely (pre-reads + p1's read).
    STAGE_A(0, 0, 0); STAGE_B(0, 0); STAGE_A(0, 1, 0);
    STAGE_A(1, 0, 64); STAGE_B(1, 64);
    asm volatile("s_waitcnt vmcnt(4)");
    __builtin_amdgcn_s_barrier();
    RDA(aA, 0, 0); RDB(b0, 0);

    #pragma unroll 1
    for (int j = 0; j < niter - 1; ++j) {
        // p1: buf0.q0 [aA,b0] ; read aB<-buf0.A1
        RDA(aB, 0, 1); STAGE_A(1, 1, 64);
        MMA(acc[0], aA, b0);
        asm volatile("s_waitcnt vmcnt(2)");
        __builtin_amdgcn_s_barrier();
        // p2: buf0.q1 [aB,b0] ; read aA<-buf1.A0, b1<-buf1.B
        RDA(aA, 1, 0); RDB(b1, 1); STAGE_A(0, 0, 128); STAGE_B(0, 128);
        MMA(acc[1], aB, b0);
        asm volatile("s_waitcnt vmcnt(4)");
        __builtin_amdgcn_s_barrier();
        // p3: buf1.q0 [aA,b1] ; read aB<-buf1.A1
        RDA(aB, 1, 1); STAGE_A(0, 1, 128);
        MMA(acc[0], aA, b1);
        asm volatile("s_waitcnt vmcnt(2)");
        __builtin_amdgcn_s_barrier();
        // p4: buf1.q1 [aB,b1] ; read aA<-buf0.A0, b0<-buf0.B (tile 2j+2)
        RDA(aA, 0, 0); RDB(b0, 0); STAGE_A(1, 0, 192); STAGE_B(1, 192);
        MMA(acc[1], aB, b1);
        asm volatile("s_waitcnt vmcnt(4)");
        __builtin_amdgcn_s_barrier();

        aP += 128; bP += 128;
    }

    // peeled final iteration (buf0=nt-2, buf1=nt-1): p1 stage real;
    // p2..p4 dead (clamped +64); p4's next-tile reads skipped.
    {
        RDA(aB, 0, 1); STAGE_A(1, 1, 64);
        MMA(acc[0], aA, b0);
        asm volatile("s_waitcnt vmcnt(2)");
        __builtin_amdgcn_s_barrier();
        RDA(aA, 1, 0); RDB(b1, 1); STAGE_A(0, 0, 64); STAGE_B(0, 64);
        MMA(acc[1], aB, b0);
        asm volatile("s_waitcnt vmcnt(4)");
        __builtin_amdgcn_s_barrier();
        RDA(aB, 1, 1); STAGE_A(0, 1, 64);
        MMA(acc[0], aA, b1);
        asm volatile("s_waitcnt vmcnt(2)");
        __builtin_amdgcn_s_barrier();
        MMA(acc[1], aB, b1);
    }

    // drain async LDS writes before epilogue/endpgm (LDS realloc hazard)
    asm volatile("s_waitcnt vmcnt(0)");

    // D mapping per 16x16 frag: col = lane&15, row = quad*4 + r.
    #pragma unroll
    for (int qr = 0; qr < 2; qr++) {
        const long row0 = m0 + qr * 128 + wrq * 32 + quad * 4;
        #pragma unroll
        for (int ni = 0; ni < 4; ni++) {
            const long col = n0 + wcq * 64 + ni * 16 + m16;
            if (EPI == 0) {
                u16* C = (u16*)Cp + (long)b * cBatch;
                const float bv = bias ? bias[col] : 0.f;
                #pragma unroll
                for (int mi = 0; mi < 2; mi++)
                    #pragma unroll
                    for (int r = 0; r < 4; r++)
                        C[(row0 + mi * 16 + r) * ldc + col] =
                            f2bf(acc[qr][mi][ni][r] + bv);
            } else if (EPI == 1) {
                u16* C = (u16*)Cp + (long)b * cBatch;
                #pragma unroll
                for (int mi = 0; mi < 2; mi++)
                    #pragma unroll
                    for (int r = 0; r < 4; r++)
                        C[(row0 + mi * 16 + r) * ldc + col] =
                            f2bf(acc[qr][mi][ni][r] * scale);
            } else {
                float* C = (float*)Cp + (long)b * cBatch;
                const float bv = bias ? bias[col] : 0.f;
                #pragma unroll
                for (int mi = 0; mi < 2; mi++)
                    #pragma unroll
                    for (int r = 0; r < 4; r++)
                        C[(row0 + mi * 16 + r) * ldc + col] =
                            acc[qr][mi][ni][r] + bv;
            }
        }
    }
}

// in-place masked row softmax over 2048 bf16 (f32 math). 1 block per row.
__global__ __launch_bounds__(256) void softmax2048(u16* __restrict__ S,
                                                   const int* __restrict__ mask) {
    const long row = blockIdx.x;
    u16* p = S + row * SEQ;
    const int* mrow = mask + row * SEQ;
    const int tid = threadIdx.x;

    short8 v = *(const short8*)(p + tid * 8);
    uint4 mw0 = *(const uint4*)(mrow + tid * 8);
    uint4 mw1 = *(const uint4*)(mrow + tid * 8 + 4);
    const unsigned int* mwv = (const unsigned int*)&mw0;

    float f[8];
    #pragma unroll
    for (int j = 0; j < 8; j++) {
        const unsigned int mv = (j < 4) ? mwv[j] : ((const unsigned int*)&mw1)[j - 4];
        f[j] = (mv == 0u) ? 1e-10f : bf2f((u16)v[j]);
    }

    float m = f[0];
    #pragma unroll
    for (int j = 1; j < 8; j++) m = fmaxf(m, f[j]);
    #pragma unroll
    for (int i = 1; i < 64; i <<= 1) m = fmaxf(m, __shfl_xor(m, i));

    __shared__ float redm[4], reds[4];
    if ((tid & 63) == 0) redm[tid >> 6] = m;
    __syncthreads();
    m = fmaxf(fmaxf(redm[0], redm[1]), fmaxf(redm[2], redm[3]));

    float e[8], s = 0.f;
    #pragma unroll
    for (int j = 0; j < 8; j++) { e[j] = __expf(f[j] - m); s += e[j]; }
    #pragma unroll
    for (int i = 1; i < 64; i <<= 1) s += __shfl_xor(s, i);
    if ((tid & 63) == 0) reds[tid >> 6] = s;
    __syncthreads();
    s = reds[0] + reds[1] + reds[2] + reds[3];

    const float inv = 1.f / s;
    short8 o;
    #pragma unroll
    for (int j = 0; j < 8; j++) o[j] = (short)f2bf(e[j] * inv);
    *(short8*)(p + tid * 8) = o;
}

extern "C" void kernel_launch(void* const* d_in, const int* in_sizes, int n_in,
                              void* d_out, int out_size, void* d_ws, size_t ws_size,
                              hipStream_t stream) {
    const float* x    = (const float*)d_in[0];
    const int*   mask = (const int*)d_in[1];
    const float* Wqkv = (const float*)d_in[2];
    const float* bqkv = (const float*)d_in[3];
    const float* Wout = (const float*)d_in[4];
    const float* bout = (const float*)d_in[5];
    float* out = (float*)d_out;

    char* ws = (char*)d_ws;
    // ws layout, total 102,760,448 bytes:
    //   [0,        16777216) xh  bf16 [8192][1024]          (cvt -> K1)
    //   [16777216, 23068672) wqt bf16 [3072][1024]          (cvt -> K1)
    //   [0,        33554432) sc  bf16 [4][2048][2048]       (K2 -> K4; xh,wqt dead)
    //   [33554432, 35651584) wot bf16 [1024][1024]          (cvt -> K5)
    //   [35651584, 85983232) qkv bf16 [8192][3072]          (K1 -> K2)
    //   [35651584, 52428800) attn bf16 [8192][1024]         (K4 -> K5; qkv dead)
    //   [85983232,102760448) vt  bf16 [4][1024][2048]       (transpose_v -> K4)
    u16* xh   = (u16*)(ws + 0);
    u16* wqt  = (u16*)(ws + 16777216);
    u16* sc   = (u16*)(ws + 0);
    u16* wot  = (u16*)(ws + 33554432);
    u16* qkv  = (u16*)(ws + 35651584);
    u16* attn = (u16*)(ws + 35651584);
    u16* vt   = (u16*)(ws + 85983232);

    cvt_bf16<<<4096, 256, 0, stream>>>(x, xh, 8388608);
    transpose_cvt<<<dim3(96, 32), 256, 0, stream>>>(Wqkv, wqt, 1024, 3072);
    transpose_cvt<<<dim3(32, 32), 256, 0, stream>>>(Wout, wot, 1024, 1024);

    // K1: qkv = x @ Wqkv + bqkv   (M=8192, N=3072, K=1024), bf16 out
    //     768 blocks = 3.0 exact rounds
    gemm256n128<0><<<dim3(24, 32, 1), 512, 0, stream>>>(
        xh, 1024, 0, wqt, 1024, 0, qkv, 3072, 0, bqkv, 1.f, 1024);

    // V slice -> vt [b][d][s]
    transpose_v<<<dim3(32, 64, NB), 256, 0, stream>>>(qkv, vt);

    // K2: sc[b] = (Q[b] @ K[b]^T)/32   (M=2048, N=2048, K=1024), bf16 out
    //     256x128 tile -> 16x8x4 = 512 blocks = 2.0 exact rounds
    //     (replaces the spilling 256x256 read-ahead kernel)
    gemm256n128<1><<<dim3(16, 8, NB), 512, 0, stream>>>(
        qkv, 3072, (long)SEQ * 3072, qkv + 1024, 3072, (long)SEQ * 3072,
        sc, SEQ, (long)SEQ * SEQ, nullptr, 0.03125f, 1024);

    // K3: masked softmax rows (mask==0 -> 1e-10, f32 math, bf16 storage)
    softmax2048<<<dim3(NB * SEQ), 256, 0, stream>>>(sc, mask);

    // K4: attn[b] = P[b] @ V[b]   (M=2048, N=1024, K=2048), bf16 out
    gemm256n128<0><<<dim3(8, 8, NB), 512, 0, stream>>>(
        sc, SEQ, (long)SEQ * SEQ, vt, SEQ, (long)1024 * SEQ,
        attn, 1024, (long)SEQ * 1024, nullptr, 1.f, 2048);

    // K5: out = attn @ Wout + bout   (M=8192, N=1024, K=1024), f32 out
    gemm256n128<2><<<dim3(8, 32, 1), 512, 0, stream>>>(
        attn, 1024, 0, wot, 1024, 0, out, 1024, 0, bout, 1.f, 1024);
}